// Round 1
// baseline (384.240 us; speedup 1.0000x reference)
//
#include <hip/hip_runtime.h>
#include <hip/hip_bf16.h>

#define BATCH 8192
#define DK    2048   // d_embed + d_hidden (GEMM K)
#define DH    1024   // hidden
#define DN    4096   // 4 gates * DH (GEMM N)

typedef __attribute__((ext_vector_type(8))) short bf16x8;
typedef __attribute__((ext_vector_type(4))) short short4v;
typedef __attribute__((ext_vector_type(4))) float f32x4;

__device__ __forceinline__ unsigned short f2bf(float f) {
    union { float f; unsigned u; } v; v.f = f;
    unsigned r = v.u + 0x7FFFu + ((v.u >> 16) & 1u);   // RNE
    return (unsigned short)(r >> 16);
}
__device__ __forceinline__ float bf2f(unsigned short b) {
    union { unsigned u; float f; } v; v.u = ((unsigned)b) << 16; return v.f;
}
__device__ __forceinline__ float sigm(float x)  { return 1.0f / (1.0f + __expf(-x)); }
__device__ __forceinline__ float tanh_(float x) { return 1.0f - 2.0f / (1.0f + __expf(2.0f * x)); }

__device__ __forceinline__ void glds16(const void* g, void* l) {
    __builtin_amdgcn_global_load_lds(
        (const __attribute__((address_space(1))) unsigned*)g,
        (__attribute__((address_space(3))) unsigned*)l, 16, 0, 0);
}

// ---------------- 1. concat(x,h) -> bf16 A[8192][2048] ----------------
__global__ void cvtA_k(const float* __restrict__ x, const float* __restrict__ h,
                       short* __restrict__ A) {
    long t = (long)blockIdx.x * 256 + threadIdx.x;     // 1,048,576 threads
    long idx = t << 3;                                 // 8 f32 each
    long b   = idx >> 10;
    int  col = (int)(idx & 1023);
    {
        float4 v0 = *(const float4*)(x + idx);
        float4 v1 = *(const float4*)(x + idx + 4);
        bf16x8 s;
        s[0]=(short)f2bf(v0.x); s[1]=(short)f2bf(v0.y); s[2]=(short)f2bf(v0.z); s[3]=(short)f2bf(v0.w);
        s[4]=(short)f2bf(v1.x); s[5]=(short)f2bf(v1.y); s[6]=(short)f2bf(v1.z); s[7]=(short)f2bf(v1.w);
        *(bf16x8*)(A + b * DK + col) = s;
    }
    {
        float4 v0 = *(const float4*)(h + idx);
        float4 v1 = *(const float4*)(h + idx + 4);
        bf16x8 s;
        s[0]=(short)f2bf(v0.x); s[1]=(short)f2bf(v0.y); s[2]=(short)f2bf(v0.z); s[3]=(short)f2bf(v0.w);
        s[4]=(short)f2bf(v1.x); s[5]=(short)f2bf(v1.y); s[6]=(short)f2bf(v1.z); s[7]=(short)f2bf(v1.w);
        *(bf16x8*)(A + b * DK + 1024 + col) = s;
    }
}

// ---------------- 2. W[2048][1024] -> bf16 Wt[1024][2048] (one gate) ----------------
__global__ void cvtW_k(const float* __restrict__ Wg, short* __restrict__ Wt) {
    __shared__ float tile[64][65];                     // +1 pad: conflict-free transpose
    int k0 = blockIdx.x << 6;                          // 32 tiles
    int j0 = blockIdx.y << 6;                          // 16 tiles
    int tid = threadIdx.x;
    int rr = tid >> 4, c4 = (tid & 15) << 2;
#pragma unroll
    for (int i = 0; i < 4; i++) {
        int r = rr + (i << 4);
        float4 v = *(const float4*)(Wg + (long)(k0 + r) * DH + j0 + c4);
        tile[r][c4] = v.x; tile[r][c4+1] = v.y; tile[r][c4+2] = v.z; tile[r][c4+3] = v.w;
    }
    __syncthreads();
#pragma unroll
    for (int i = 0; i < 4; i++) {
        int jr = rr + (i << 4);
        short4v s;
        s[0]=(short)f2bf(tile[c4+0][jr]); s[1]=(short)f2bf(tile[c4+1][jr]);
        s[2]=(short)f2bf(tile[c4+2][jr]); s[3]=(short)f2bf(tile[c4+3][jr]);
        *(short4v*)(Wt + (long)(j0 + jr) * DK + k0 + c4) = s;
    }
}

// ---------------- 3. GEMM: G[8192][4096] = A[8192][2048] x Wt^T, bf16 MFMA ----------------
// 128x128 tile, BK=32, 4 waves (2x2), double-buffered LDS, global_load_lds w=16,
// XOR swizzle f(r)=(r^(r>>2))&3 on the 16B k-slot (pre-swizzled source + swizzled read).
__launch_bounds__(256, 2)
__global__ void gemm_k(const short* __restrict__ A, const short* __restrict__ W,
                       short* __restrict__ G) {
    __shared__ short sA[2][4096];
    __shared__ short sB[2][4096];

    int bid = blockIdx.x;
    int wg  = ((bid & 7) << 8) + (bid >> 3);           // XCD swizzle, 2048 % 8 == 0
    int nt  = wg >> 6;                                 // 0..31  (shares W panel per chunk)
    int mt  = wg & 63;                                 // 0..63
    int tid = threadIdx.x;
    int lane = tid & 63;
    int wv = tid >> 6, wr = wv >> 1, wc = wv & 1;

    long baseA[2], baseB[2];
    int  ldso[2];
#pragma unroll
    for (int c = 0; c < 2; c++) {
        int r  = (c << 6) + (tid >> 2);
        int s  = tid & 3;
        int ss = s ^ ((r ^ (r >> 2)) & 3);             // inverse-swizzled global slot
        baseA[c] = (long)(mt * 128 + r) * DK + ss * 8;
        baseB[c] = (long)(nt * 128 + r) * DK + ss * 8;
        ldso[c]  = (c << 12) + (tid << 4);             // linear LDS dest (bytes)
    }

    int offA[4], offB[4];
#pragma unroll
    for (int i = 0; i < 4; i++) {
        int rA = (wr << 6) + (i << 4) + (lane & 15);
        offA[i] = (rA << 6) + ((((lane >> 4)) ^ ((rA ^ (rA >> 2)) & 3)) << 4);
        int rB = (wc << 6) + (i << 4) + (lane & 15);
        offB[i] = (rB << 6) + ((((lane >> 4)) ^ ((rB ^ (rB >> 2)) & 3)) << 4);
    }

    f32x4 acc[4][4];
    const f32x4 fz = {0.f, 0.f, 0.f, 0.f};
#pragma unroll
    for (int i = 0; i < 4; i++)
#pragma unroll
        for (int j = 0; j < 4; j++) acc[i][j] = fz;

    auto STAGE = [&](int buf, int kt) {
        const short* a0 = A + (long)kt * 32;
        const short* b0 = W + (long)kt * 32;
        char* la = (char*)&sA[buf][0];
        char* lb = (char*)&sB[buf][0];
#pragma unroll
        for (int c = 0; c < 2; c++) {
            glds16(a0 + baseA[c], la + ldso[c]);
            glds16(b0 + baseB[c], lb + ldso[c]);
        }
    };
    auto COMPUTE = [&](int buf) {
        const char* la = (const char*)&sA[buf][0];
        const char* lb = (const char*)&sB[buf][0];
        bf16x8 av[4], bv[4];
#pragma unroll
        for (int i = 0; i < 4; i++) {
            av[i] = *(const bf16x8*)(la + offA[i]);
            bv[i] = *(const bf16x8*)(lb + offB[i]);
        }
#pragma unroll
        for (int i = 0; i < 4; i++)
#pragma unroll
            for (int j = 0; j < 4; j++)
                acc[i][j] = __builtin_amdgcn_mfma_f32_16x16x32_bf16(av[i], bv[j], acc[i][j], 0, 0, 0);
    };

    STAGE(0, 0);
    __syncthreads();                                   // drains vmcnt before barrier
    int cur = 0;
    for (int kt = 1; kt < DK / 32; ++kt) {
        STAGE(cur ^ 1, kt);
        COMPUTE(cur);
        __syncthreads();
        cur ^= 1;
    }
    COMPUTE(cur);

    // C-write: D row = (lane>>4)*4 + reg, col = lane&15  [m89-verified layout]
    long row0 = (long)mt * 128 + (wr << 6) + ((lane >> 4) << 2);
    int  col0 = nt * 128 + (wc << 6) + (lane & 15);
#pragma unroll
    for (int i = 0; i < 4; i++)
#pragma unroll
        for (int j = 0; j < 4; j++) {
            long r = row0 + (i << 4);
            int  cc = col0 + (j << 4);
#pragma unroll
            for (int q = 0; q < 4; q++)
                G[(r + q) * DN + cc] = (short)f2bf(acc[i][j][q]);
        }
}

// ---------------- 4. epilogue: bias + activations + LSTM combine ----------------
__global__ void ep_k(const short* __restrict__ G, const float* __restrict__ cin,
                     const float* __restrict__ bfv, const float* __restrict__ biv,
                     const float* __restrict__ bov, const float* __restrict__ buv,
                     float* __restrict__ out) {
    long t = (long)blockIdx.x * 256 + threadIdx.x;
    long idx = t << 3;                                 // 8 cols each
    long b   = idx >> 10;
    int  col = (int)(idx & 1023);
    long gb  = b << 12;                                // * 4096

    bf16x8 fg = *(const bf16x8*)(G + gb + col);
    bf16x8 ig = *(const bf16x8*)(G + gb + 1024 + col);
    bf16x8 og = *(const bf16x8*)(G + gb + 2048 + col);
    bf16x8 ug = *(const bf16x8*)(G + gb + 3072 + col);

    float4 c0 = *(const float4*)(cin + idx), c1 = *(const float4*)(cin + idx + 4);
    float4 f0 = *(const float4*)(bfv + col), f1 = *(const float4*)(bfv + col + 4);
    float4 i0 = *(const float4*)(biv + col), i1 = *(const float4*)(biv + col + 4);
    float4 o0 = *(const float4*)(bov + col), o1 = *(const float4*)(bov + col + 4);
    float4 u0 = *(const float4*)(buv + col), u1 = *(const float4*)(buv + col + 4);

    float cv[8] = {c0.x,c0.y,c0.z,c0.w,c1.x,c1.y,c1.z,c1.w};
    float ba[8] = {f0.x,f0.y,f0.z,f0.w,f1.x,f1.y,f1.z,f1.w};
    float bb[8] = {i0.x,i0.y,i0.z,i0.w,i1.x,i1.y,i1.z,i1.w};
    float bc[8] = {o0.x,o0.y,o0.z,o0.w,o1.x,o1.y,o1.z,o1.w};
    float bd[8] = {u0.x,u0.y,u0.z,u0.w,u1.x,u1.y,u1.z,u1.w};

    float hv[8], ncv[8];
#pragma unroll
    for (int q = 0; q < 8; q++) {
        float f  = sigm(bf2f((unsigned short)fg[q]) + ba[q]);
        float i_ = sigm(bf2f((unsigned short)ig[q]) + bb[q]);
        float o_ = sigm(bf2f((unsigned short)og[q]) + bc[q]);
        float u_ = tanh_(bf2f((unsigned short)ug[q]) + bd[q]);
        float nc = f * cv[q] + i_ * u_;
        ncv[q] = nc;
        hv[q]  = o_ * tanh_(nc);
    }
    float4 h0 = {hv[0],hv[1],hv[2],hv[3]},  h1 = {hv[4],hv[5],hv[6],hv[7]};
    float4 n0 = {ncv[0],ncv[1],ncv[2],ncv[3]}, n1 = {ncv[4],ncv[5],ncv[6],ncv[7]};
    *(float4*)(out + idx)     = h0;
    *(float4*)(out + idx + 4) = h1;
    *(float4*)(out + (long)BATCH * DH + idx)     = n0;
    *(float4*)(out + (long)BATCH * DH + idx + 4) = n1;
}

// ---------------- fallback (ws too small): naive f32 ----------------
__global__ void naive_k(const float* __restrict__ x, const float* __restrict__ h,
                        const float* __restrict__ cin,
                        const float* __restrict__ Wf, const float* __restrict__ bfv,
                        const float* __restrict__ Wi, const float* __restrict__ biv,
                        const float* __restrict__ Wo, const float* __restrict__ bov,
                        const float* __restrict__ Wu, const float* __restrict__ buv,
                        float* __restrict__ out) {
    long t = (long)blockIdx.x * 256 + threadIdx.x;
    long b = t >> 10; int j = (int)(t & 1023);
    float sf = bfv[j], si = biv[j], so = bov[j], su = buv[j];
    for (int k = 0; k < 1024; k++) {
        float xv = x[b * 1024 + k];
        long w = (long)k * 1024 + j;
        sf += xv * Wf[w]; si += xv * Wi[w]; so += xv * Wo[w]; su += xv * Wu[w];
    }
    for (int k = 0; k < 1024; k++) {
        float hv = h[b * 1024 + k];
        long w = (long)(k + 1024) * 1024 + j;
        sf += hv * Wf[w]; si += hv * Wi[w]; so += hv * Wo[w]; su += hv * Wu[w];
    }
    float f = sigm(sf), i_ = sigm(si), o_ = sigm(so), u_ = tanh_(su);
    float nc = f * cin[t] + i_ * u_;
    out[t] = o_ * tanh_(nc);
    out[(long)BATCH * DH + t] = nc;
}

extern "C" void kernel_launch(void* const* d_in, const int* in_sizes, int n_in,
                              void* d_out, int out_size, void* d_ws, size_t ws_size,
                              hipStream_t stream) {
    const float* x   = (const float*)d_in[0];
    const float* h   = (const float*)d_in[1];
    const float* c   = (const float*)d_in[2];
    const float* Wf  = (const float*)d_in[3];
    const float* bf_ = (const float*)d_in[4];
    const float* Wi  = (const float*)d_in[5];
    const float* bi_ = (const float*)d_in[6];
    const float* Wo  = (const float*)d_in[7];
    const float* bo_ = (const float*)d_in[8];
    const float* Wu  = (const float*)d_in[9];
    const float* bu_ = (const float*)d_in[10];
    float* out = (float*)d_out;

    const size_t needA = (size_t)BATCH * DK * 2;       // 33.55 MB
    const size_t needW = (size_t)DN * DK * 2;          // 16.78 MB
    const size_t needG = (size_t)BATCH * DN * 2;       // 67.11 MB

    if (ws_size < needA + needW + needG) {
        naive_k<<<(BATCH * DH) / 256, 256, 0, stream>>>(x, h, c, Wf, bf_, Wi, bi_, Wo, bo_, Wu, bu_, out);
        return;
    }

    short* Abf = (short*)d_ws;
    short* Wt  = (short*)((char*)d_ws + needA);
    short* G   = (short*)((char*)d_ws + needA + needW);

    cvtA_k<<<(BATCH * DH) / (256 * 8), 256, 0, stream>>>(x, h, Abf);
    dim3 tg(DK / 64, DH / 64);
    cvtW_k<<<tg, 256, 0, stream>>>(Wf, Wt + 0L * DH * DK / 1024 * 1024);
    cvtW_k<<<tg, 256, 0, stream>>>(Wi, Wt + 1L * DH * DK);
    cvtW_k<<<tg, 256, 0, stream>>>(Wo, Wt + 2L * DH * DK);
    cvtW_k<<<tg, 256, 0, stream>>>(Wu, Wt + 3L * DH * DK);
    gemm_k<<<(BATCH / 128) * (DN / 128), 256, 0, stream>>>(Abf, Wt, G);
    ep_k<<<(BATCH * DH) / (256 * 8), 256, 0, stream>>>(G, c, bf_, bi_, bo_, bu_, out);
}

// Round 2
// 354.212 us; speedup vs baseline: 1.0848x; 1.0848x over previous
//
#include <hip/hip_runtime.h>
#include <hip/hip_bf16.h>

#define BATCH 8192
#define DK    2048   // d_embed + d_hidden (GEMM K)
#define DH    1024   // hidden
#define DN    4096   // 4 gates * DH
#define NT    64     // K-tiles of 32

typedef __attribute__((ext_vector_type(8))) short bf16x8;
typedef __attribute__((ext_vector_type(4))) short short4v;
typedef __attribute__((ext_vector_type(4))) float f32x4;

__device__ __forceinline__ unsigned short f2bf(float f) {
    union { float f; unsigned u; } v; v.f = f;
    unsigned r = v.u + 0x7FFFu + ((v.u >> 16) & 1u);   // RNE
    return (unsigned short)(r >> 16);
}
__device__ __forceinline__ float sigm(float x)  { return 1.0f / (1.0f + __expf(-x)); }
__device__ __forceinline__ float tanh_(float x) { return 1.0f - 2.0f / (1.0f + __expf(2.0f * x)); }

__device__ __forceinline__ void glds16(const void* g, void* l) {
    __builtin_amdgcn_global_load_lds(
        (const __attribute__((address_space(1))) unsigned*)g,
        (__attribute__((address_space(3))) unsigned*)l, 16, 0, 0);
}

// ---------------- 1. concat(x,h) -> bf16 A[8192][2048] ----------------
__global__ void cvtA_k(const float* __restrict__ x, const float* __restrict__ h,
                       short* __restrict__ A) {
    long t = (long)blockIdx.x * 256 + threadIdx.x;
    long idx = t << 3;
    long b   = idx >> 10;
    int  col = (int)(idx & 1023);
    {
        float4 v0 = *(const float4*)(x + idx);
        float4 v1 = *(const float4*)(x + idx + 4);
        bf16x8 s;
        s[0]=(short)f2bf(v0.x); s[1]=(short)f2bf(v0.y); s[2]=(short)f2bf(v0.z); s[3]=(short)f2bf(v0.w);
        s[4]=(short)f2bf(v1.x); s[5]=(short)f2bf(v1.y); s[6]=(short)f2bf(v1.z); s[7]=(short)f2bf(v1.w);
        *(bf16x8*)(A + b * DK + col) = s;
    }
    {
        float4 v0 = *(const float4*)(h + idx);
        float4 v1 = *(const float4*)(h + idx + 4);
        bf16x8 s;
        s[0]=(short)f2bf(v0.x); s[1]=(short)f2bf(v0.y); s[2]=(short)f2bf(v0.z); s[3]=(short)f2bf(v0.w);
        s[4]=(short)f2bf(v1.x); s[5]=(short)f2bf(v1.y); s[6]=(short)f2bf(v1.z); s[7]=(short)f2bf(v1.w);
        *(bf16x8*)(A + b * DK + 1024 + col) = s;
    }
}

// ---------------- 2. all 4 gates: W[2048][1024] -> Wt[4096][2048], gate-interleaved ----
// Output row n = (hid>>4)*64 + gate*16 + (hid&15): every 64-row group = 16 hids x 4 gates.
__global__ void cvtW_k(const float* __restrict__ W0, const float* __restrict__ W1,
                       const float* __restrict__ W2, const float* __restrict__ W3,
                       short* __restrict__ Wt) {
    __shared__ float tile[64][65];
    const int g = blockIdx.z;
    const float* Wg = (g == 0) ? W0 : (g == 1) ? W1 : (g == 2) ? W2 : W3;
    int k0 = blockIdx.x << 6;
    int j0 = blockIdx.y << 6;
    int tid = threadIdx.x;
    int rr = tid >> 4, c4 = (tid & 15) << 2;
#pragma unroll
    for (int i = 0; i < 4; i++) {
        int r = rr + (i << 4);
        float4 v = *(const float4*)(Wg + (long)(k0 + r) * DH + j0 + c4);
        tile[r][c4] = v.x; tile[r][c4+1] = v.y; tile[r][c4+2] = v.z; tile[r][c4+3] = v.w;
    }
    __syncthreads();
#pragma unroll
    for (int i = 0; i < 4; i++) {
        int jr = rr + (i << 4);
        int j  = j0 + jr;
        int n  = ((j >> 4) << 6) + (g << 4) + (j & 15);
        short4v s;
        s[0]=(short)f2bf(tile[c4+0][jr]); s[1]=(short)f2bf(tile[c4+1][jr]);
        s[2]=(short)f2bf(tile[c4+2][jr]); s[3]=(short)f2bf(tile[c4+3][jr]);
        *(short4v*)(Wt + (long)n * DK + k0 + c4) = s;
    }
}

// ---------------- 3. fused GEMM + LSTM epilogue ----------------
// 256x256 tile, BK=32, 8 waves (2M x 4N), ring-4 LDS buffers, counted vmcnt(8),
// raw s_barrier (1/K-tile), setprio around MFMA, LDS swizzle slot^=(row>>1)&3.
// Wave wc owns 16 hids x 4 gates (fragments g=0..3) -> epilogue is lane-local.
__launch_bounds__(512, 1)
__global__ void gemm_k(const short* __restrict__ A, const short* __restrict__ W,
                       const float* __restrict__ cin,
                       const float* __restrict__ bfv, const float* __restrict__ biv,
                       const float* __restrict__ bov, const float* __restrict__ buv,
                       float* __restrict__ out) {
    __shared__ char sA[65536];   // 4 bufs x 16KB ([256][32] bf16)
    __shared__ char sB[65536];

    const int bid = blockIdx.x;
    const int wg  = ((bid & 7) << 6) + (bid >> 3);   // XCD swizzle, 512 % 8 == 0
    const int nt  = wg >> 5;        // 0..15
    const int mt  = wg & 31;        // 0..31
    const int tid = threadIdx.x;
    const int lane = tid & 63;
    const int wv = tid >> 6;
    const int wr = wv >> 2;         // 0..1 (M half)
    const int wc = wv & 3;          // 0..3 (col group = 16 hids)

    // staging addresses (pre-swizzled global source, linear LDS dest)
    const int srow  = tid >> 2;                       // 0..127
    const int sslot = (tid & 3) ^ ((tid >> 3) & 3);   // inverse swizzle
    const long a0 = (long)(mt * 256 + srow)       * DK + sslot * 8;
    const long a1 = (long)(mt * 256 + 128 + srow) * DK + sslot * 8;
    const long b0 = (long)(nt * 256 + srow)       * DK + sslot * 8;
    const long b1 = (long)(nt * 256 + 128 + srow) * DK + sslot * 8;

    // fragment LDS byte offsets (swizzled read side)
    int offA[8], offB[4];
#pragma unroll
    for (int i = 0; i < 8; i++) {
        int rA = (wr << 7) + (i << 4) + (lane & 15);
        offA[i] = (rA << 6) + (((lane >> 4) ^ ((rA >> 1) & 3)) << 4);
    }
#pragma unroll
    for (int g = 0; g < 4; g++) {
        int rB = (wc << 6) + (g << 4) + (lane & 15);
        offB[g] = (rB << 6) + (((lane >> 4) ^ ((rB >> 1) & 3)) << 4);
    }

    f32x4 acc[8][4];
    const f32x4 fz = {0.f, 0.f, 0.f, 0.f};
#pragma unroll
    for (int i = 0; i < 8; i++)
#pragma unroll
        for (int g = 0; g < 4; g++) acc[i][g] = fz;

    auto STAGE = [&](int t) {
        const int buf = t & 3;
        char* la = sA + (buf << 14) + (tid << 4);
        char* lb = sB + (buf << 14) + (tid << 4);
        const long ko = (long)t << 5;
        glds16(A + a0 + ko, la);
        glds16(A + a1 + ko, la + 8192);
        glds16(W + b0 + ko, lb);
        glds16(W + b1 + ko, lb + 8192);
    };

    auto BODY = [&](int t, bool doStage, int vml) {
        const int bo2 = (t & 3) << 14;
        if (doStage) STAGE(t + 3);                    // overwrites buf consumed at t-1
        bf16x8 bv[4], av[4];
#pragma unroll
        for (int g = 0; g < 4; g++) bv[g] = *(const bf16x8*)(sB + bo2 + offB[g]);
#pragma unroll
        for (int i = 0; i < 4; i++) av[i] = *(const bf16x8*)(sA + bo2 + offA[i]);
        __builtin_amdgcn_s_setprio(1);
#pragma unroll
        for (int i = 0; i < 4; i++)
#pragma unroll
            for (int g = 0; g < 4; g++)
                acc[i][g] = __builtin_amdgcn_mfma_f32_16x16x32_bf16(av[i], bv[g], acc[i][g], 0, 0, 0);
        __builtin_amdgcn_s_setprio(0);
#pragma unroll
        for (int i = 0; i < 4; i++) av[i] = *(const bf16x8*)(sA + bo2 + offA[i + 4]);
        __builtin_amdgcn_s_setprio(1);
#pragma unroll
        for (int i = 0; i < 4; i++)
#pragma unroll
            for (int g = 0; g < 4; g++)
                acc[i + 4][g] = __builtin_amdgcn_mfma_f32_16x16x32_bf16(av[i], bv[g], acc[i + 4][g], 0, 0, 0);
        __builtin_amdgcn_s_setprio(0);
        if (vml == 8)      asm volatile("s_waitcnt vmcnt(8)" ::: "memory");
        else if (vml == 4) asm volatile("s_waitcnt vmcnt(4)" ::: "memory");
        else if (vml == 0) asm volatile("s_waitcnt vmcnt(0)" ::: "memory");
        if (vml >= 0) __builtin_amdgcn_s_barrier();
    };

    // prologue: 3 tiles in flight, wait tile0 (own 4 of 12 loads drained)
    STAGE(0); STAGE(1); STAGE(2);
    asm volatile("s_waitcnt vmcnt(8)" ::: "memory");
    __builtin_amdgcn_s_barrier();

#pragma unroll 1
    for (int t = 0; t <= NT - 4; ++t) BODY(t, true, 8);
    BODY(NT - 3, false, 4);
    BODY(NT - 2, false, 0);
    BODY(NT - 1, false, -1);

    // fused LSTM epilogue: acc[i][0..3] = f,i,o,u pre-activations (lane-local)
    const int hid = nt * 64 + wc * 16 + (lane & 15);
    const long rowb = (long)mt * 256 + (wr << 7) + ((lane >> 4) << 2);
    const float b_f = bfv[hid], b_i = biv[hid], b_o = bov[hid], b_u = buv[hid];
#pragma unroll
    for (int i = 0; i < 8; i++) {
#pragma unroll
        for (int q = 0; q < 4; q++) {
            const long r = rowb + (i << 4) + q;
            float f  = sigm(acc[i][0][q] + b_f);
            float i_ = sigm(acc[i][1][q] + b_i);
            float o_ = sigm(acc[i][2][q] + b_o);
            float u_ = tanh_(acc[i][3][q] + b_u);
            float nc = f * cin[r * DH + hid] + i_ * u_;
            out[r * DH + hid] = o_ * tanh_(nc);
            out[(long)BATCH * DH + r * DH + hid] = nc;
        }
    }
}

// ---------------- fallback (ws too small): naive f32 ----------------
__global__ void naive_k(const float* __restrict__ x, const float* __restrict__ h,
                        const float* __restrict__ cin,
                        const float* __restrict__ Wf, const float* __restrict__ bfv,
                        const float* __restrict__ Wi, const float* __restrict__ biv,
                        const float* __restrict__ Wo, const float* __restrict__ bov,
                        const float* __restrict__ Wu, const float* __restrict__ buv,
                        float* __restrict__ out) {
    long t = (long)blockIdx.x * 256 + threadIdx.x;
    long b = t >> 10; int j = (int)(t & 1023);
    float sf = bfv[j], si = biv[j], so = bov[j], su = buv[j];
    for (int k = 0; k < 1024; k++) {
        float xv = x[b * 1024 + k];
        long w = (long)k * 1024 + j;
        sf += xv * Wf[w]; si += xv * Wi[w]; so += xv * Wo[w]; su += xv * Wu[w];
    }
    for (int k = 0; k < 1024; k++) {
        float hv = h[b * 1024 + k];
        long w = (long)(k + 1024) * 1024 + j;
        sf += hv * Wf[w]; si += hv * Wi[w]; so += hv * Wo[w]; su += hv * Wu[w];
    }
    float f = sigm(sf), i_ = sigm(si), o_ = sigm(so), u_ = tanh_(su);
    float nc = f * cin[t] + i_ * u_;
    out[t] = o_ * tanh_(nc);
    out[(long)BATCH * DH + t] = nc;
}

extern "C" void kernel_launch(void* const* d_in, const int* in_sizes, int n_in,
                              void* d_out, int out_size, void* d_ws, size_t ws_size,
                              hipStream_t stream) {
    const float* x   = (const float*)d_in[0];
    const float* h   = (const float*)d_in[1];
    const float* c   = (const float*)d_in[2];
    const float* Wf  = (const float*)d_in[3];
    const float* bf_ = (const float*)d_in[4];
    const float* Wi  = (const float*)d_in[5];
    const float* bi_ = (const float*)d_in[6];
    const float* Wo  = (const float*)d_in[7];
    const float* bo_ = (const float*)d_in[8];
    const float* Wu  = (const float*)d_in[9];
    const float* bu_ = (const float*)d_in[10];
    float* out = (float*)d_out;

    const size_t needA = (size_t)BATCH * DK * 2;   // 33.55 MB
    const size_t needW = (size_t)DN * DK * 2;      // 16.78 MB

    if (ws_size < needA + needW) {
        naive_k<<<(BATCH * DH) / 256, 256, 0, stream>>>(x, h, c, Wf, bf_, Wi, bi_, Wo, bo_, Wu, bu_, out);
        return;
    }

    short* Abf = (short*)d_ws;
    short* Wt  = (short*)((char*)d_ws + needA);

    cvtA_k<<<(BATCH * DH) / (256 * 8), 256, 0, stream>>>(x, h, Abf);
    cvtW_k<<<dim3(DK / 64, DH / 64, 4), 256, 0, stream>>>(Wf, Wi, Wo, Wu, Wt);
    gemm_k<<<512, 512, 0, stream>>>(Abf, Wt, c, bf_, bi_, bo_, bu_, out);
}

// Round 3
// 348.593 us; speedup vs baseline: 1.1023x; 1.0161x over previous
//
#include <hip/hip_runtime.h>
#include <hip/hip_bf16.h>

#define BATCH 8192
#define DK    2048   // d_embed + d_hidden (GEMM K)
#define DH    1024   // hidden
#define DN    4096   // 4 gates * DH
#define NT    64     // K-tiles of 32

typedef __attribute__((ext_vector_type(8))) short bf16x8;
typedef __attribute__((ext_vector_type(4))) short short4v;
typedef __attribute__((ext_vector_type(4))) float f32x4;

__device__ __forceinline__ unsigned short f2bf(float f) {
    union { float f; unsigned u; } v; v.f = f;
    unsigned r = v.u + 0x7FFFu + ((v.u >> 16) & 1u);   // RNE
    return (unsigned short)(r >> 16);
}
__device__ __forceinline__ float sigm(float x)  { return 1.0f / (1.0f + __expf(-x)); }
__device__ __forceinline__ float tanh_(float x) { return 1.0f - 2.0f / (1.0f + __expf(2.0f * x)); }

__device__ __forceinline__ void glds16(const void* g, void* l) {
    __builtin_amdgcn_global_load_lds(
        (const __attribute__((address_space(1))) unsigned*)g,
        (__attribute__((address_space(3))) unsigned*)l, 16, 0, 0);
}

// ---------------- 1. concat(x,h) -> bf16 A[8192][2048] ----------------
__global__ void cvtA_k(const float* __restrict__ x, const float* __restrict__ h,
                       short* __restrict__ A) {
    long t = (long)blockIdx.x * 256 + threadIdx.x;
    long idx = t << 3;
    long b   = idx >> 10;
    int  col = (int)(idx & 1023);
    {
        float4 v0 = *(const float4*)(x + idx);
        float4 v1 = *(const float4*)(x + idx + 4);
        bf16x8 s;
        s[0]=(short)f2bf(v0.x); s[1]=(short)f2bf(v0.y); s[2]=(short)f2bf(v0.z); s[3]=(short)f2bf(v0.w);
        s[4]=(short)f2bf(v1.x); s[5]=(short)f2bf(v1.y); s[6]=(short)f2bf(v1.z); s[7]=(short)f2bf(v1.w);
        *(bf16x8*)(A + b * DK + col) = s;
    }
    {
        float4 v0 = *(const float4*)(h + idx);
        float4 v1 = *(const float4*)(h + idx + 4);
        bf16x8 s;
        s[0]=(short)f2bf(v0.x); s[1]=(short)f2bf(v0.y); s[2]=(short)f2bf(v0.z); s[3]=(short)f2bf(v0.w);
        s[4]=(short)f2bf(v1.x); s[5]=(short)f2bf(v1.y); s[6]=(short)f2bf(v1.z); s[7]=(short)f2bf(v1.w);
        *(bf16x8*)(A + b * DK + 1024 + col) = s;
    }
}

// ---------------- 2. all 4 gates: W[2048][1024] -> Wt[4096][2048], gate-interleaved ----
__global__ void cvtW_k(const float* __restrict__ W0, const float* __restrict__ W1,
                       const float* __restrict__ W2, const float* __restrict__ W3,
                       short* __restrict__ Wt) {
    __shared__ float tile[64][65];
    const int g = blockIdx.z;
    const float* Wg = (g == 0) ? W0 : (g == 1) ? W1 : (g == 2) ? W2 : W3;
    int k0 = blockIdx.x << 6;
    int j0 = blockIdx.y << 6;
    int tid = threadIdx.x;
    int rr = tid >> 4, c4 = (tid & 15) << 2;
#pragma unroll
    for (int i = 0; i < 4; i++) {
        int r = rr + (i << 4);
        float4 v = *(const float4*)(Wg + (long)(k0 + r) * DH + j0 + c4);
        tile[r][c4] = v.x; tile[r][c4+1] = v.y; tile[r][c4+2] = v.z; tile[r][c4+3] = v.w;
    }
    __syncthreads();
#pragma unroll
    for (int i = 0; i < 4; i++) {
        int jr = rr + (i << 4);
        int j  = j0 + jr;
        int n  = ((j >> 4) << 6) + (g << 4) + (j & 15);
        short4v s;
        s[0]=(short)f2bf(tile[c4+0][jr]); s[1]=(short)f2bf(tile[c4+1][jr]);
        s[2]=(short)f2bf(tile[c4+2][jr]); s[3]=(short)f2bf(tile[c4+3][jr]);
        *(short4v*)(Wt + (long)n * DK + k0 + c4) = s;
    }
}

// ---------------- 3. fused GEMM + LSTM epilogue, 2-sub-phase schedule ----------------
// 256x256, BK=32, 8 waves (2Mx4N), ring-4 LDS, counted vmcnt(8) at K-tile boundary ONLY,
// raw s_barrier (no vmcnt-0 drain), per-phase {stage||ds_read -> bar -> lgkm0 -> 16 MFMA -> bar},
// setprio around MFMA clusters. Wave wc owns 16 hids x 4 gates -> lane-local LSTM epilogue.
__launch_bounds__(512, 1)
__global__ void gemm_k(const short* __restrict__ A, const short* __restrict__ W,
                       const float* __restrict__ cin,
                       const float* __restrict__ bfv, const float* __restrict__ biv,
                       const float* __restrict__ bov, const float* __restrict__ buv,
                       float* __restrict__ out) {
    __shared__ char sA[65536];   // 4 bufs x 16KB ([256][32] bf16)
    __shared__ char sB[65536];

    const int bid = blockIdx.x;
    const int wg  = ((bid & 7) << 6) + (bid >> 3);   // XCD swizzle, 512 % 8 == 0
    const int nt  = wg >> 5;        // 0..15
    const int mt  = wg & 31;        // 0..31
    const int tid = threadIdx.x;
    const int lane = tid & 63;
    const int wv = tid >> 6;
    const int wr = wv >> 2;         // 0..1 (M half)
    const int wc = wv & 3;          // 0..3 (col group = 16 hids)

    // staging addresses (pre-swizzled global source, linear LDS dest)  [round-2 verified]
    const int srow  = tid >> 2;                       // 0..127
    const int sslot = (tid & 3) ^ ((tid >> 3) & 3);   // inverse swizzle
    const long a0 = (long)(mt * 256 + srow)       * DK + sslot * 8;
    const long a1 = (long)(mt * 256 + 128 + srow) * DK + sslot * 8;
    const long b0 = (long)(nt * 256 + srow)       * DK + sslot * 8;
    const long b1 = (long)(nt * 256 + 128 + srow) * DK + sslot * 8;

    // fragment LDS byte offsets (swizzled read side)  [round-2: conflicts == 0]
    int offA[8], offB[4];
#pragma unroll
    for (int i = 0; i < 8; i++) {
        int rA = (wr << 7) + (i << 4) + (lane & 15);
        offA[i] = (rA << 6) + (((lane >> 4) ^ ((rA >> 1) & 3)) << 4);
    }
#pragma unroll
    for (int g = 0; g < 4; g++) {
        int rB = (wc << 6) + (g << 4) + (lane & 15);
        offB[g] = (rB << 6) + (((lane >> 4) ^ ((rB >> 1) & 3)) << 4);
    }

    f32x4 acc[8][4];
    const f32x4 fz = {0.f, 0.f, 0.f, 0.f};
#pragma unroll
    for (int i = 0; i < 8; i++)
#pragma unroll
        for (int g = 0; g < 4; g++) acc[i][g] = fz;

    auto STAGEA = [&](int t) {
        char* la = sA + ((t & 3) << 14) + (tid << 4);
        const long ko = (long)t << 5;
        glds16(A + a0 + ko, la);
        glds16(A + a1 + ko, la + 8192);
    };
    auto STAGEB = [&](int t) {
        char* lb = sB + ((t & 3) << 14) + (tid << 4);
        const long ko = (long)t << 5;
        glds16(W + b0 + ko, lb);
        glds16(W + b1 + ko, lb + 8192);
    };

    // BODY(t): two sub-phases; vml = vmcnt gate at K-tile end (-1 = none, fall out)
    auto BODY = [&](int t, bool doStage, int vml) {
        const int bo2 = (t & 3) << 14;
        bf16x8 bv[4], av[4];
        // ---- sub-phase 0: stage A(t+3) || read B0-3, A0-3 ----
        if (doStage) STAGEA(t + 3);
#pragma unroll
        for (int g = 0; g < 4; g++) bv[g] = *(const bf16x8*)(sB + bo2 + offB[g]);
#pragma unroll
        for (int i = 0; i < 4; i++) av[i] = *(const bf16x8*)(sA + bo2 + offA[i]);
        __builtin_amdgcn_sched_barrier(0);
        __builtin_amdgcn_s_barrier();
        asm volatile("s_waitcnt lgkmcnt(0)" ::: "memory");
        __builtin_amdgcn_sched_barrier(0);
        __builtin_amdgcn_s_setprio(1);
#pragma unroll
        for (int i = 0; i < 4; i++)
#pragma unroll
            for (int g = 0; g < 4; g++)
                acc[i][g] = __builtin_amdgcn_mfma_f32_16x16x32_bf16(av[i], bv[g], acc[i][g], 0, 0, 0);
        __builtin_amdgcn_s_setprio(0);
        __builtin_amdgcn_sched_barrier(0);
        __builtin_amdgcn_s_barrier();
        __builtin_amdgcn_sched_barrier(0);
        // ---- sub-phase 1: stage B(t+3) || read A4-7 ----
        if (doStage) STAGEB(t + 3);
#pragma unroll
        for (int i = 0; i < 4; i++) av[i] = *(const bf16x8*)(sA + bo2 + offA[i + 4]);
        __builtin_amdgcn_sched_barrier(0);
        __builtin_amdgcn_s_barrier();
        asm volatile("s_waitcnt lgkmcnt(0)" ::: "memory");
        __builtin_amdgcn_sched_barrier(0);
        __builtin_amdgcn_s_setprio(1);
#pragma unroll
        for (int i = 0; i < 4; i++)
#pragma unroll
            for (int g = 0; g < 4; g++)
                acc[i + 4][g] = __builtin_amdgcn_mfma_f32_16x16x32_bf16(av[i], bv[g], acc[i + 4][g], 0, 0, 0);
        __builtin_amdgcn_s_setprio(0);
        __builtin_amdgcn_sched_barrier(0);
        // ---- K-tile boundary: counted vmcnt gate (never 0 mid-loop), then barrier ----
        if (vml == 8)      asm volatile("s_waitcnt vmcnt(8)" ::: "memory");
        else if (vml == 4) asm volatile("s_waitcnt vmcnt(4)" ::: "memory");
        else if (vml == 0) asm volatile("s_waitcnt vmcnt(0)" ::: "memory");
        if (vml >= 0) {
            __builtin_amdgcn_s_barrier();
            __builtin_amdgcn_sched_barrier(0);
        }
    };

    // prologue: 3 K-tiles in flight (12 loads/thread), tile0 guaranteed by vmcnt(8)
    STAGEA(0); STAGEB(0); STAGEA(1); STAGEB(1); STAGEA(2); STAGEB(2);
    asm volatile("s_waitcnt vmcnt(8)" ::: "memory");
    __builtin_amdgcn_s_barrier();
    __builtin_amdgcn_sched_barrier(0);

#pragma unroll 1
    for (int t = 0; t <= NT - 4; ++t) BODY(t, true, 8);
    BODY(NT - 3, false, 4);
    BODY(NT - 2, false, 0);
    BODY(NT - 1, false, -1);

    // fused LSTM epilogue: acc[i][0..3] = f,i,o,u pre-activations (lane-local)
    const int hid = nt * 64 + wc * 16 + (lane & 15);
    const long rowb = (long)mt * 256 + (wr << 7) + ((lane >> 4) << 2);
    const float b_f = bfv[hid], b_i = biv[hid], b_o = bov[hid], b_u = buv[hid];
#pragma unroll
    for (int i = 0; i < 8; i++) {
#pragma unroll
        for (int q = 0; q < 4; q++) {
            const long r = rowb + (i << 4) + q;
            float f  = sigm(acc[i][0][q] + b_f);
            float i_ = sigm(acc[i][1][q] + b_i);
            float o_ = sigm(acc[i][2][q] + b_o);
            float u_ = tanh_(acc[i][3][q] + b_u);
            float nc = f * cin[r * DH + hid] + i_ * u_;
            out[r * DH + hid] = o_ * tanh_(nc);
            out[(long)BATCH * DH + r * DH + hid] = nc;
        }
    }
}

// ---------------- fallback (ws too small): naive f32 ----------------
__global__ void naive_k(const float* __restrict__ x, const float* __restrict__ h,
                        const float* __restrict__ cin,
                        const float* __restrict__ Wf, const float* __restrict__ bfv,
                        const float* __restrict__ Wi, const float* __restrict__ biv,
                        const float* __restrict__ Wo, const float* __restrict__ bov,
                        const float* __restrict__ Wu, const float* __restrict__ buv,
                        float* __restrict__ out) {
    long t = (long)blockIdx.x * 256 + threadIdx.x;
    long b = t >> 10; int j = (int)(t & 1023);
    float sf = bfv[j], si = biv[j], so = bov[j], su = buv[j];
    for (int k = 0; k < 1024; k++) {
        float xv = x[b * 1024 + k];
        long w = (long)k * 1024 + j;
        sf += xv * Wf[w]; si += xv * Wi[w]; so += xv * Wo[w]; su += xv * Wu[w];
    }
    for (int k = 0; k < 1024; k++) {
        float hv = h[b * 1024 + k];
        long w = (long)(k + 1024) * 1024 + j;
        sf += hv * Wf[w]; si += hv * Wi[w]; so += hv * Wo[w]; su += hv * Wu[w];
    }
    float f = sigm(sf), i_ = sigm(si), o_ = sigm(so), u_ = tanh_(su);
    float nc = f * cin[t] + i_ * u_;
    out[t] = o_ * tanh_(nc);
    out[(long)BATCH * DH + t] = nc;
}

extern "C" void kernel_launch(void* const* d_in, const int* in_sizes, int n_in,
                              void* d_out, int out_size, void* d_ws, size_t ws_size,
                              hipStream_t stream) {
    const float* x   = (const float*)d_in[0];
    const float* h   = (const float*)d_in[1];
    const float* c   = (const float*)d_in[2];
    const float* Wf  = (const float*)d_in[3];
    const float* bf_ = (const float*)d_in[4];
    const float* Wi  = (const float*)d_in[5];
    const float* bi_ = (const float*)d_in[6];
    const float* Wo  = (const float*)d_in[7];
    const float* bo_ = (const float*)d_in[8];
    const float* Wu  = (const float*)d_in[9];
    const float* bu_ = (const float*)d_in[10];
    float* out = (float*)d_out;

    const size_t needA = (size_t)BATCH * DK * 2;   // 33.55 MB
    const size_t needW = (size_t)DN * DK * 2;      // 16.78 MB

    if (ws_size < needA + needW) {
        naive_k<<<(BATCH * DH) / 256, 256, 0, stream>>>(x, h, c, Wf, bf_, Wi, bi_, Wo, bo_, Wu, bu_, out);
        return;
    }

    short* Abf = (short*)d_ws;
    short* Wt  = (short*)((char*)d_ws + needA);

    cvtA_k<<<(BATCH * DH) / (256 * 8), 256, 0, stream>>>(x, h, Abf);
    cvtW_k<<<dim3(DK / 64, DH / 64, 4), 256, 0, stream>>>(Wf, Wi, Wo, Wu, Wt);
    gemm_k<<<512, 512, 0, stream>>>(Abf, Wt, c, bf_, bi_, bo_, bu_, out);
}